// Round 2
// baseline (3019.691 us; speedup 1.0000x reference)
//
#include <hip/hip_runtime.h>
#include <math.h>

typedef unsigned short u16;
typedef __attribute__((ext_vector_type(8))) short bf16x8;
typedef __attribute__((ext_vector_type(4))) float f32x4;
typedef __attribute__((ext_vector_type(2))) unsigned short u16x2;
typedef __attribute__((ext_vector_type(4))) unsigned short u16x4;

#define DEV static __device__ __forceinline__

DEV float bf2f(u16 h) {
  union { unsigned int u; float f; } v; v.u = ((unsigned int)h) << 16; return v.f;
}
DEV u16 f2bf(float f) {
  union { float f; unsigned int u; } v; v.f = f;
  return (u16)((v.u + 0x7FFFu + ((v.u >> 16) & 1u)) >> 16);
}
DEV float siluf(float x) { return x / (1.f + __expf(-x)); }
DEV f32x4 mfma16(bf16x8 a, bf16x8 b, f32x4 c) {
  return __builtin_amdgcn_mfma_f32_16x16x32_bf16(a, b, c, 0, 0, 0);
}

// ---------------------------------------------------------------------------
// K0: f32 -> bf16 weight conversion (one-time per launch)
// ---------------------------------------------------------------------------
__global__ __launch_bounds__(256) void k_f2bf(const float* __restrict__ s,
                                              u16* __restrict__ d, int n) {
  int i = blockIdx.x * 256 + threadIdx.x;
  if (i < n) d[i] = f2bf(s[i]);
}

// ---------------------------------------------------------------------------
// K1: G[il][d] = sum_n Z[n][il] * x[n][d]  (il=c*128+l, 384x256, K=N split)
//     plus xsum[d] = sum_n x[n][d].  fp32 atomics into zeroed ws buffers.
// ---------------------------------------------------------------------------
__global__ __launch_bounds__(256) void k_greduce(
    const float* __restrict__ x, const float* __restrict__ Z,
    float* __restrict__ Gbuf, float* __restrict__ xsum, int N)
{
  const int tx = threadIdx.x & 15, ty = threadIdx.x >> 4;
  const int d0 = blockIdx.y * 128 + tx * 8;
  const int m0 = blockIdx.z * 128 + ty * 8;
  const int nk = gridDim.x;
  const int chunk = (N + nk - 1) / nk;
  const int k0 = blockIdx.x * chunk;
  const int k1 = (k0 + chunk < N) ? (k0 + chunk) : N;

  float acc[8][8];
#pragma unroll
  for (int i = 0; i < 8; ++i)
#pragma unroll
    for (int j = 0; j < 8; ++j) acc[i][j] = 0.f;
  float xs[8];
#pragma unroll
  for (int j = 0; j < 8; ++j) xs[j] = 0.f;
  const bool doxs = (blockIdx.z == 0) && (ty == 0);

  for (int k = k0; k < k1; ++k) {
    float4 z0 = *(const float4*)(Z + (size_t)k * 384 + m0);
    float4 z1 = *(const float4*)(Z + (size_t)k * 384 + m0 + 4);
    float4 x0 = *(const float4*)(x + (size_t)k * 256 + d0);
    float4 x1 = *(const float4*)(x + (size_t)k * 256 + d0 + 4);
    float zf[8] = {z0.x, z0.y, z0.z, z0.w, z1.x, z1.y, z1.z, z1.w};
    float xf[8] = {x0.x, x0.y, x0.z, x0.w, x1.x, x1.y, x1.z, x1.w};
#pragma unroll
    for (int i = 0; i < 8; ++i)
#pragma unroll
      for (int j = 0; j < 8; ++j) acc[i][j] = fmaf(zf[i], xf[j], acc[i][j]);
    if (doxs) {
#pragma unroll
      for (int j = 0; j < 8; ++j) xs[j] += xf[j];
    }
  }
#pragma unroll
  for (int i = 0; i < 8; ++i)
#pragma unroll
    for (int j = 0; j < 8; ++j)
      atomicAdd(&Gbuf[(size_t)(m0 + i) * 256 + (d0 + j)], acc[i][j]);
  if (doxs) {
#pragma unroll
    for (int j = 0; j < 8; ++j) atomicAdd(&xsum[d0 + j], xs[j]);
  }
}

// ---------------------------------------------------------------------------
// K2: ZXT[d][c*128+l] = coeff*( sum_i zcw[c][i]*G[i*128+l][d] + zcb[c]*xsum[d] )
// bf16 output, d-major so the t-GEMM B-fragment is a contiguous 16B load.
// ---------------------------------------------------------------------------
__global__ __launch_bounds__(256) void k_zxt(
    const float* __restrict__ Gbuf, const float* __restrict__ xsum,
    const float* __restrict__ zcw, const float* __restrict__ zcb,
    u16* __restrict__ ZXT, float coeff)
{
  const int cl = blockIdx.x;
  const int d = threadIdx.x;
  const int c = cl >> 7, l = cl & 127;
  float v = zcb[c] * xsum[d];
#pragma unroll
  for (int i = 0; i < 3; ++i)
    v += zcw[c * 3 + i] * Gbuf[(size_t)(i * 128 + l) * 256 + d];
  ZXT[(size_t)d * 384 + cl] = f2bf(coeff * v);
}

// ---------------------------------------------------------------------------
// K3: xij branch. 32 edges/block. p=xi*xj -> GEMM1(256, silu) -> GEMM2(768)
//     -> LN -> prod = xij
// ---------------------------------------------------------------------------
__global__ __launch_bounds__(256) void k_xij(
    const float* __restrict__ x, const int* __restrict__ tei, int E,
    const u16* __restrict__ w1, const float* __restrict__ b1,
    const u16* __restrict__ w2, const float* __restrict__ b2,
    const float* __restrict__ lng, const float* __restrict__ lnb,
    u16* __restrict__ prod)
{
  __shared__ __align__(16) u16 pl[32 * 264];
  __shared__ __align__(16) u16 hl[32 * 264];
  __shared__ float sArr[4][32], ssArr[4][32];
  __shared__ int sidx[64];
  const int tid = threadIdx.x;
  const int lane = tid & 63, wid = tid >> 6;
  const int col = lane & 15, qd = lane >> 4;
  const int e0 = blockIdx.x * 32;

  if (tid < 32) sidx[tid] = tei[e0 + tid];
  else if (tid < 64) sidx[tid] = tei[E + e0 + (tid - 32)];
  __syncthreads();

  for (int e = wid; e < 32; e += 4) {
    float4 va = ((const float4*)(x + (size_t)sidx[e] * 256))[lane];
    float4 vb = ((const float4*)(x + (size_t)sidx[32 + e] * 256))[lane];
    u16x4 pv;
    pv[0] = f2bf(va.x * vb.x);
    pv[1] = f2bf(va.y * vb.y);
    pv[2] = f2bf(va.z * vb.z);
    pv[3] = f2bf(va.w * vb.w);
    *(u16x4*)(pl + e * 264 + lane * 4) = pv;
  }
  __syncthreads();

  { // GEMM1: h = silu(p @ w1^T + b1), N=256, per-wave o-range 64
    f32x4 acc1[2][4];
#pragma unroll
    for (int mf = 0; mf < 2; ++mf)
#pragma unroll
      for (int nf = 0; nf < 4; ++nf) acc1[mf][nf] = (f32x4){0.f, 0.f, 0.f, 0.f};
    const int oo = wid * 64;
    for (int kk = 0; kk < 256; kk += 32) {
      bf16x8 a0 = *(const bf16x8*)(pl + col * 264 + kk + qd * 8);
      bf16x8 a1 = *(const bf16x8*)(pl + (16 + col) * 264 + kk + qd * 8);
#pragma unroll
      for (int nf = 0; nf < 4; ++nf) {
        bf16x8 bv = *(const bf16x8*)(w1 + (size_t)(oo + nf * 16 + col) * 256 + kk + qd * 8);
        acc1[0][nf] = mfma16(a0, bv, acc1[0][nf]);
        acc1[1][nf] = mfma16(a1, bv, acc1[1][nf]);
      }
    }
#pragma unroll
    for (int nf = 0; nf < 4; ++nf) {
      const int o = oo + nf * 16 + col;
      const float bias = b1[o];
#pragma unroll
      for (int mf = 0; mf < 2; ++mf)
#pragma unroll
        for (int j = 0; j < 4; ++j)
          hl[(mf * 16 + qd * 4 + j) * 264 + o] = f2bf(siluf(acc1[mf][nf][j] + bias));
    }
  }
  __syncthreads();

  // GEMM2: u = h @ w2^T + b2, N=768, per-wave o-range 192
  f32x4 acc[2][12];
#pragma unroll
  for (int mf = 0; mf < 2; ++mf)
#pragma unroll
    for (int nf = 0; nf < 12; ++nf) acc[mf][nf] = (f32x4){0.f, 0.f, 0.f, 0.f};
  const int o0 = wid * 192;
  for (int kk = 0; kk < 256; kk += 32) {
    bf16x8 a0 = *(const bf16x8*)(hl + col * 264 + kk + qd * 8);
    bf16x8 a1 = *(const bf16x8*)(hl + (16 + col) * 264 + kk + qd * 8);
#pragma unroll
    for (int nf = 0; nf < 12; ++nf) {
      bf16x8 bv = *(const bf16x8*)(w2 + (size_t)(o0 + nf * 16 + col) * 256 + kk + qd * 8);
      acc[0][nf] = mfma16(a0, bv, acc[0][nf]);
      acc[1][nf] = mfma16(a1, bv, acc[1][nf]);
    }
  }
#pragma unroll
  for (int nf = 0; nf < 12; ++nf) {
    const float bias = b2[o0 + nf * 16 + col];
#pragma unroll
    for (int mf = 0; mf < 2; ++mf)
#pragma unroll
      for (int j = 0; j < 4; ++j) acc[mf][nf][j] += bias;
  }
  float s[2][4], ss[2][4];
#pragma unroll
  for (int mf = 0; mf < 2; ++mf)
#pragma unroll
    for (int j = 0; j < 4; ++j) {
      float a = 0.f, b = 0.f;
#pragma unroll
      for (int nf = 0; nf < 12; ++nf) { float v = acc[mf][nf][j]; a += v; b += v * v; }
      s[mf][j] = a; ss[mf][j] = b;
    }
#pragma unroll
  for (int m = 1; m < 16; m <<= 1) {
#pragma unroll
    for (int mf = 0; mf < 2; ++mf)
#pragma unroll
      for (int j = 0; j < 4; ++j) {
        s[mf][j] += __shfl_xor(s[mf][j], m, 16);
        ss[mf][j] += __shfl_xor(ss[mf][j], m, 16);
      }
  }
  if (col == 0) {
#pragma unroll
    for (int mf = 0; mf < 2; ++mf)
#pragma unroll
      for (int j = 0; j < 4; ++j) {
        sArr[wid][mf * 16 + qd * 4 + j] = s[mf][j];
        ssArr[wid][mf * 16 + qd * 4 + j] = ss[mf][j];
      }
  }
  __syncthreads();
  float mean[2][4], rstd[2][4];
#pragma unroll
  for (int mf = 0; mf < 2; ++mf)
#pragma unroll
    for (int j = 0; j < 4; ++j) {
      const int e = mf * 16 + qd * 4 + j;
      float S = sArr[0][e] + sArr[1][e] + sArr[2][e] + sArr[3][e];
      float SS = ssArr[0][e] + ssArr[1][e] + ssArr[2][e] + ssArr[3][e];
      float mu = S * (1.f / 768.f);
      float var = fmaxf(SS * (1.f / 768.f) - mu * mu, 0.f);
      mean[mf][j] = mu;
      rstd[mf][j] = rsqrtf(var + 1e-5f);
    }
#pragma unroll
  for (int nf = 0; nf < 12; ++nf) {
    const int o = o0 + nf * 16 + col;
    const float gv = lng[o], bv = lnb[o];
#pragma unroll
    for (int mf = 0; mf < 2; ++mf)
#pragma unroll
      for (int j = 0; j < 4; ++j) {
        const int e = mf * 16 + qd * 4 + j;
        float v = (acc[mf][nf][j] - mean[mf][j]) * rstd[mf][j] * gv + bv;
        prod[(size_t)(e0 + e) * 768 + o] = f2bf(v);
      }
  }
}

// ---------------------------------------------------------------------------
// K4: xz branch. 16 edges/block. rxz (3x3 dots, f32) -> g1 both orders (silu)
//     -> dual GEMM768 -> silu -> LN each -> sum -> prod *=
// ---------------------------------------------------------------------------
__global__ __launch_bounds__(256) void k_xz(
    const float* __restrict__ Z, const int* __restrict__ tei, int E,
    const float* __restrict__ zw1, const float* __restrict__ zb1,
    const u16* __restrict__ zw2, const float* __restrict__ zb2,
    const float* __restrict__ lng, const float* __restrict__ lnb,
    u16* __restrict__ prod)
{
  __shared__ __align__(16) float zst[32 * 384];
  __shared__ __align__(16) u16 g1s[2 * 16 * 264];
  __shared__ float rxzf[16 * 9];
  __shared__ float sArr[2][4][16], ssArr[2][4][16];
  __shared__ int sidx[32];
  const int tid = threadIdx.x;
  const int lane = tid & 63, wid = tid >> 6;
  const int col = lane & 15, qd = lane >> 4;
  const int e0 = blockIdx.x * 16;

  if (tid < 16) sidx[tid] = tei[e0 + tid];
  else if (tid < 32) sidx[tid] = tei[E + e0 + (tid - 16)];
  __syncthreads();

  for (int r = wid; r < 32; r += 4) {
    const int e = r >> 1;
    const int idx = (r & 1) ? sidx[16 + e] : sidx[e];
    const float2* src = (const float2*)(Z + (size_t)idx * 384);
    float2* dst = (float2*)(zst + r * 384);
#pragma unroll
    for (int p = 0; p < 3; ++p) dst[p * 64 + lane] = src[p * 64 + lane];
  }
  __syncthreads();

  if (tid < 144) {  // 16 edges x 9 (c,cc) dot products over L=128
    const int e = tid / 9, p = tid % 9, c = p / 3, cc = p % 3;
    const float* zi = zst + (e * 2) * 384 + c * 128;
    const float* zj = zst + (e * 2 + 1) * 384 + cc * 128;
    float a = 0.f;
    for (int l = 0; l < 128; ++l) a = fmaf(zi[l], zj[l], a);
    rxzf[tid] = a * (1.f / 128.f);
  }
  __syncthreads();

  {
    const int o = tid;  // 0..255
    float w9[9];
#pragma unroll
    for (int kk = 0; kk < 9; ++kk) w9[kk] = zw1[o * 9 + kk];
    const float bb = zb1[o];
    for (int se = 0; se < 32; ++se) {
      const int side = se >> 4, e = se & 15;
      float v = bb;
#pragma unroll
      for (int kk = 0; kk < 9; ++kk) {
        const int pp = side ? ((kk % 3) * 3 + (kk / 3)) : kk;
        v += rxzf[e * 9 + pp] * w9[kk];
      }
      g1s[side * (16 * 264) + e * 264 + o] = f2bf(siluf(v));
    }
  }
  __syncthreads();

  f32x4 aca[12], acb[12];
#pragma unroll
  for (int nf = 0; nf < 12; ++nf) {
    aca[nf] = (f32x4){0.f, 0.f, 0.f, 0.f};
    acb[nf] = (f32x4){0.f, 0.f, 0.f, 0.f};
  }
  const int o0 = wid * 192;
  for (int kk = 0; kk < 256; kk += 32) {
    bf16x8 aa = *(const bf16x8*)(g1s + col * 264 + kk + qd * 8);
    bf16x8 ab = *(const bf16x8*)(g1s + (16 * 264) + col * 264 + kk + qd * 8);
#pragma unroll
    for (int nf = 0; nf < 12; ++nf) {
      bf16x8 bv = *(const bf16x8*)(zw2 + (size_t)(o0 + nf * 16 + col) * 256 + kk + qd * 8);
      aca[nf] = mfma16(aa, bv, aca[nf]);
      acb[nf] = mfma16(ab, bv, acb[nf]);
    }
  }
  // second SiLU of zlin, THEN LayerNorm
#pragma unroll
  for (int nf = 0; nf < 12; ++nf) {
    const float bias = zb2[o0 + nf * 16 + col];
#pragma unroll
    for (int j = 0; j < 4; ++j) {
      aca[nf][j] = siluf(aca[nf][j] + bias);
      acb[nf][j] = siluf(acb[nf][j] + bias);
    }
  }
  float sa[4], ssa[4], sb[4], ssb[4];
#pragma unroll
  for (int j = 0; j < 4; ++j) {
    float A = 0.f, B = 0.f, C = 0.f, D = 0.f;
#pragma unroll
    for (int nf = 0; nf < 12; ++nf) {
      float v = aca[nf][j]; A += v; B += v * v;
      float w = acb[nf][j]; C += w; D += w * w;
    }
    sa[j] = A; ssa[j] = B; sb[j] = C; ssb[j] = D;
  }
#pragma unroll
  for (int m = 1; m < 16; m <<= 1) {
#pragma unroll
    for (int j = 0; j < 4; ++j) {
      sa[j] += __shfl_xor(sa[j], m, 16);
      ssa[j] += __shfl_xor(ssa[j], m, 16);
      sb[j] += __shfl_xor(sb[j], m, 16);
      ssb[j] += __shfl_xor(ssb[j], m, 16);
    }
  }
  if (col == 0) {
#pragma unroll
    for (int j = 0; j < 4; ++j) {
      sArr[0][wid][qd * 4 + j] = sa[j]; ssArr[0][wid][qd * 4 + j] = ssa[j];
      sArr[1][wid][qd * 4 + j] = sb[j]; ssArr[1][wid][qd * 4 + j] = ssb[j];
    }
  }
  __syncthreads();
  float meanA[4], rstdA[4], meanB[4], rstdB[4];
#pragma unroll
  for (int j = 0; j < 4; ++j) {
    const int e = qd * 4 + j;
    float S = sArr[0][0][e] + sArr[0][1][e] + sArr[0][2][e] + sArr[0][3][e];
    float SS = ssArr[0][0][e] + ssArr[0][1][e] + ssArr[0][2][e] + ssArr[0][3][e];
    float mu = S * (1.f / 768.f);
    meanA[j] = mu;
    rstdA[j] = rsqrtf(fmaxf(SS * (1.f / 768.f) - mu * mu, 0.f) + 1e-5f);
    S = sArr[1][0][e] + sArr[1][1][e] + sArr[1][2][e] + sArr[1][3][e];
    SS = ssArr[1][0][e] + ssArr[1][1][e] + ssArr[1][2][e] + ssArr[1][3][e];
    mu = S * (1.f / 768.f);
    meanB[j] = mu;
    rstdB[j] = rsqrtf(fmaxf(SS * (1.f / 768.f) - mu * mu, 0.f) + 1e-5f);
  }
#pragma unroll
  for (int nf = 0; nf < 12; ++nf) {
    const int o = o0 + nf * 16 + col;
    const float gv = lng[o], bv = lnb[o];
#pragma unroll
    for (int j = 0; j < 4; ++j) {
      const int e = qd * 4 + j;
      float va = (aca[nf][j] - meanA[j]) * rstdA[j] * gv + bv;
      float vb = (acb[nf][j] - meanB[j]) * rstdB[j] * gv + bv;
      const size_t ix = (size_t)(e0 + e) * 768 + o;
      prod[ix] = f2bf(bf2f(prod[ix]) * (va + vb));
    }
  }
}

// ---------------------------------------------------------------------------
// K5: t = (Zi*Zj) @ ZXT^T -> xzx = LN(t @ zxw^T + zxb) -> out = sum_o
//     prod*xzx*lin_w + lin_b.   32 edges/block.  f32 output.
// ---------------------------------------------------------------------------
__global__ __launch_bounds__(256) void k_final(
    const float* __restrict__ Z, const int* __restrict__ tei, int E,
    const u16* __restrict__ ZXT,
    const u16* __restrict__ zxw, const float* __restrict__ zxb,
    const float* __restrict__ lng, const float* __restrict__ lnb,
    const u16* __restrict__ prod,
    const float* __restrict__ lw, const float* __restrict__ lb,
    float* __restrict__ out)
{
  __shared__ __align__(16) u16 ql[32 * 392];
  __shared__ __align__(16) u16 tl[32 * 264];
  __shared__ float sArr[4][32], ssArr[4][32], oArr[4][32];
  __shared__ int sidx[64];
  const int tid = threadIdx.x;
  const int lane = tid & 63, wid = tid >> 6;
  const int col = lane & 15, qd = lane >> 4;
  const int e0 = blockIdx.x * 32;

  if (tid < 32) sidx[tid] = tei[e0 + tid];
  else if (tid < 64) sidx[tid] = tei[E + e0 + (tid - 32)];
  __syncthreads();

  for (int e = wid; e < 32; e += 4) {
    const float2* zi = (const float2*)(Z + (size_t)sidx[e] * 384);
    const float2* zj = (const float2*)(Z + (size_t)sidx[32 + e] * 384);
    u16x2* qp = (u16x2*)(ql + e * 392);
#pragma unroll
    for (int p = 0; p < 3; ++p) {
      float2 a = zi[p * 64 + lane], b = zj[p * 64 + lane];
      u16x2 r;
      r[0] = f2bf(a.x * b.x);
      r[1] = f2bf(a.y * b.y);
      qp[p * 64 + lane] = r;
    }
  }
  __syncthreads();

  { // t-GEMM: N=256 (d), K=384
    f32x4 acc1[2][4];
#pragma unroll
    for (int mf = 0; mf < 2; ++mf)
#pragma unroll
      for (int nf = 0; nf < 4; ++nf) acc1[mf][nf] = (f32x4){0.f, 0.f, 0.f, 0.f};
    const int oo = wid * 64;
    for (int kk = 0; kk < 384; kk += 32) {
      bf16x8 a0 = *(const bf16x8*)(ql + col * 392 + kk + qd * 8);
      bf16x8 a1 = *(const bf16x8*)(ql + (16 + col) * 392 + kk + qd * 8);
#pragma unroll
      for (int nf = 0; nf < 4; ++nf) {
        bf16x8 bv = *(const bf16x8*)(ZXT + (size_t)(oo + nf * 16 + col) * 384 + kk + qd * 8);
        acc1[0][nf] = mfma16(a0, bv, acc1[0][nf]);
        acc1[1][nf] = mfma16(a1, bv, acc1[1][nf]);
      }
    }
#pragma unroll
    for (int nf = 0; nf < 4; ++nf) {
      const int o = oo + nf * 16 + col;
#pragma unroll
      for (int mf = 0; mf < 2; ++mf)
#pragma unroll
        for (int j = 0; j < 4; ++j)
          tl[(mf * 16 + qd * 4 + j) * 264 + o] = f2bf(acc1[mf][nf][j]);
    }
  }
  __syncthreads();

  // xzx GEMM: N=768, K=256
  f32x4 acc[2][12];
#pragma unroll
  for (int mf = 0; mf < 2; ++mf)
#pragma unroll
    for (int nf = 0; nf < 12; ++nf) acc[mf][nf] = (f32x4){0.f, 0.f, 0.f, 0.f};
  const int o0 = wid * 192;
  for (int kk = 0; kk < 256; kk += 32) {
    bf16x8 a0 = *(const bf16x8*)(tl + col * 264 + kk + qd * 8);
    bf16x8 a1 = *(const bf16x8*)(tl + (16 + col) * 264 + kk + qd * 8);
#pragma unroll
    for (int nf = 0; nf < 12; ++nf) {
      bf16x8 bv = *(const bf16x8*)(zxw + (size_t)(o0 + nf * 16 + col) * 256 + kk + qd * 8);
      acc[0][nf] = mfma16(a0, bv, acc[0][nf]);
      acc[1][nf] = mfma16(a1, bv, acc[1][nf]);
    }
  }
#pragma unroll
  for (int nf = 0; nf < 12; ++nf) {
    const float bias = zxb[o0 + nf * 16 + col];
#pragma unroll
    for (int mf = 0; mf < 2; ++mf)
#pragma unroll
      for (int j = 0; j < 4; ++j) acc[mf][nf][j] += bias;
  }
  float s[2][4], ss[2][4];
#pragma unroll
  for (int mf = 0; mf < 2; ++mf)
#pragma unroll
    for (int j = 0; j < 4; ++j) {
      float a = 0.f, b = 0.f;
#pragma unroll
      for (int nf = 0; nf < 12; ++nf) { float v = acc[mf][nf][j]; a += v; b += v * v; }
      s[mf][j] = a; ss[mf][j] = b;
    }
#pragma unroll
  for (int m = 1; m < 16; m <<= 1) {
#pragma unroll
    for (int mf = 0; mf < 2; ++mf)
#pragma unroll
      for (int j = 0; j < 4; ++j) {
        s[mf][j] += __shfl_xor(s[mf][j], m, 16);
        ss[mf][j] += __shfl_xor(ss[mf][j], m, 16);
      }
  }
  if (col == 0) {
#pragma unroll
    for (int mf = 0; mf < 2; ++mf)
#pragma unroll
      for (int j = 0; j < 4; ++j) {
        sArr[wid][mf * 16 + qd * 4 + j] = s[mf][j];
        ssArr[wid][mf * 16 + qd * 4 + j] = ss[mf][j];
      }
  }
  __syncthreads();
  float mean[2][4], rstd[2][4];
#pragma unroll
  for (int mf = 0; mf < 2; ++mf)
#pragma unroll
    for (int j = 0; j < 4; ++j) {
      const int e = mf * 16 + qd * 4 + j;
      float S = sArr[0][e] + sArr[1][e] + sArr[2][e] + sArr[3][e];
      float SS = ssArr[0][e] + ssArr[1][e] + ssArr[2][e] + ssArr[3][e];
      float mu = S * (1.f / 768.f);
      float var = fmaxf(SS * (1.f / 768.f) - mu * mu, 0.f);
      mean[mf][j] = mu;
      rstd[mf][j] = rsqrtf(var + 1e-5f);
    }
  float pacc[2][4];
#pragma unroll
  for (int mf = 0; mf < 2; ++mf)
#pragma unroll
    for (int j = 0; j < 4; ++j) pacc[mf][j] = 0.f;
#pragma unroll
  for (int nf = 0; nf < 12; ++nf) {
    const int o = o0 + nf * 16 + col;
    const float gv = lng[o], bvq = lnb[o], lwv = lw[o];
#pragma unroll
    for (int mf = 0; mf < 2; ++mf)
#pragma unroll
      for (int j = 0; j < 4; ++j) {
        const int e = mf * 16 + qd * 4 + j;
        float xv = (acc[mf][nf][j] - mean[mf][j]) * rstd[mf][j] * gv + bvq;
        pacc[mf][j] += bf2f(prod[(size_t)(e0 + e) * 768 + o]) * xv * lwv;
      }
  }
#pragma unroll
  for (int m = 1; m < 16; m <<= 1) {
#pragma unroll
    for (int mf = 0; mf < 2; ++mf)
#pragma unroll
      for (int j = 0; j < 4; ++j) pacc[mf][j] += __shfl_xor(pacc[mf][j], m, 16);
  }
  if (col == 0) {
#pragma unroll
    for (int mf = 0; mf < 2; ++mf)
#pragma unroll
      for (int j = 0; j < 4; ++j) oArr[wid][mf * 16 + qd * 4 + j] = pacc[mf][j];
  }
  __syncthreads();
  if (tid < 32) {
    out[e0 + tid] = oArr[0][tid] + oArr[1][tid] + oArr[2][tid] + oArr[3][tid] + lb[0];
  }
}

// ---------------------------------------------------------------------------
extern "C" void kernel_launch(void* const* d_in, const int* in_sizes, int n_in,
                              void* d_out, int out_size, void* d_ws, size_t ws_size,
                              hipStream_t stream)
{
  const float* x    = (const float*)d_in[0];
  const float* Z    = (const float*)d_in[1];
  const int*   tei  = (const int*)d_in[3];
  const float* xw1  = (const float*)d_in[4];
  const float* xb1  = (const float*)d_in[5];
  const float* xw2  = (const float*)d_in[6];
  const float* xb2  = (const float*)d_in[7];
  const float* xlg  = (const float*)d_in[8];
  const float* xlb  = (const float*)d_in[9];
  const float* zw1  = (const float*)d_in[10];
  const float* zb1  = (const float*)d_in[11];
  const float* zw2  = (const float*)d_in[12];
  const float* zb2  = (const float*)d_in[13];
  const float* zlg  = (const float*)d_in[14];
  const float* zlb  = (const float*)d_in[15];
  const float* zcw  = (const float*)d_in[16];
  const float* zcb  = (const float*)d_in[17];
  const float* zxw  = (const float*)d_in[18];
  const float* zxb  = (const float*)d_in[19];
  const float* zxlg = (const float*)d_in[20];
  const float* zxlb = (const float*)d_in[21];
  const float* lw   = (const float*)d_in[22];
  const float* lb   = (const float*)d_in[23];

  const int N = in_sizes[0] / 256;
  const int E = in_sizes[3] / 2;
  if (E <= 0) return;

  char* ws = (char*)d_ws;
  u16* prod = (u16*)ws;                       // E*768 bf16
  size_t off = (size_t)E * 768 * sizeof(u16);
  float* Gbuf = (float*)(ws + off);           // 384*256 f32
  off += (size_t)384 * 256 * sizeof(float);
  float* xsum = (float*)(ws + off);           // 256 f32
  off += 256 * sizeof(float);
  u16* ZXT = (u16*)(ws + off);                // 256*384 bf16
  off += (size_t)256 * 384 * sizeof(u16);
  u16* xw1b = (u16*)(ws + off); off += (size_t)65536 * sizeof(u16);
  u16* xw2b = (u16*)(ws + off); off += (size_t)196608 * sizeof(u16);
  u16* zw2b = (u16*)(ws + off); off += (size_t)196608 * sizeof(u16);
  u16* zxwb = (u16*)(ws + off); off += (size_t)196608 * sizeof(u16);

  hipMemsetAsync(Gbuf, 0, (size_t)384 * 256 * sizeof(float) + 256 * sizeof(float), stream);

  k_f2bf<<<dim3(65536 / 256), 256, 0, stream>>>(xw1, xw1b, 65536);
  k_f2bf<<<dim3(196608 / 256), 256, 0, stream>>>(xw2, xw2b, 196608);
  k_f2bf<<<dim3(196608 / 256), 256, 0, stream>>>(zw2, zw2b, 196608);
  k_f2bf<<<dim3(196608 / 256), 256, 0, stream>>>(zxw, zxwb, 196608);

  const float coeff = 1.f / (sqrtf((float)N) * 3840.f);

  k_greduce<<<dim3(128, 2, 3), 256, 0, stream>>>(x, Z, Gbuf, xsum, N);
  k_zxt<<<dim3(384), 256, 0, stream>>>(Gbuf, xsum, zcw, zcb, ZXT, coeff);
  k_xij<<<dim3(E / 32), 256, 0, stream>>>(x, tei, E, xw1b, xb1, xw2b, xb2, xlg, xlb, prod);
  k_xz<<<dim3(E / 16), 256, 0, stream>>>(Z, tei, E, zw1, zb1, zw2b, zb2, zlg, zlb, prod);
  k_final<<<dim3(E / 32), 256, 0, stream>>>(Z, tei, E, ZXT, zxwb, zxb, zxlg, zxlb, prod, lw, lb, (float*)d_out);
}

// Round 3
// 2879.667 us; speedup vs baseline: 1.0486x; 1.0486x over previous
//
#include <hip/hip_runtime.h>
#include <math.h>

typedef unsigned short u16;
typedef __attribute__((ext_vector_type(8))) short bf16x8;
typedef __attribute__((ext_vector_type(4))) float f32x4;
typedef __attribute__((ext_vector_type(2))) unsigned short u16x2;
typedef __attribute__((ext_vector_type(4))) unsigned short u16x4;

#define DEV static __device__ __forceinline__

DEV float bf2f(u16 h) {
  union { unsigned int u; float f; } v; v.u = ((unsigned int)h) << 16; return v.f;
}
DEV u16 f2bf(float f) {
  union { float f; unsigned int u; } v; v.f = f;
  return (u16)((v.u + 0x7FFFu + ((v.u >> 16) & 1u)) >> 16);
}
DEV float siluf(float x) { return x / (1.f + __expf(-x)); }
DEV f32x4 mfma16(bf16x8 a, bf16x8 b, f32x4 c) {
  return __builtin_amdgcn_mfma_f32_16x16x32_bf16(a, b, c, 0, 0, 0);
}

// ---------------------------------------------------------------------------
// K0: f32 -> bf16 weight conversion
// ---------------------------------------------------------------------------
__global__ __launch_bounds__(256) void k_f2bf(const float* __restrict__ s,
                                              u16* __restrict__ d, int n) {
  int i = blockIdx.x * 256 + threadIdx.x;
  if (i < n) d[i] = f2bf(s[i]);
}

// ---------------------------------------------------------------------------
// K0b: build zw1 extended block [256 o][32 k] bf16: k<9 = w, k==9 = bias, 0 pad
// ---------------------------------------------------------------------------
__global__ __launch_bounds__(256) void k_w1e(const float* __restrict__ zw1,
                                             const float* __restrict__ zb1,
                                             u16* __restrict__ w1e) {
  const int o = threadIdx.x;
#pragma unroll
  for (int k = 0; k < 32; ++k) {
    float v = (k < 9) ? zw1[o * 9 + k] : ((k == 9) ? zb1[o] : 0.f);
    w1e[o * 32 + k] = f2bf(v);
  }
}

// ---------------------------------------------------------------------------
// K1: G[il][d] = sum_n Z[n][il] * x[n][d] + xsum[d] = sum_n x[n][d]
// ---------------------------------------------------------------------------
__global__ __launch_bounds__(256) void k_greduce(
    const float* __restrict__ x, const float* __restrict__ Z,
    float* __restrict__ Gbuf, float* __restrict__ xsum, int N)
{
  const int tx = threadIdx.x & 15, ty = threadIdx.x >> 4;
  const int d0 = blockIdx.y * 128 + tx * 8;
  const int m0 = blockIdx.z * 128 + ty * 8;
  const int nk = gridDim.x;
  const int chunk = (N + nk - 1) / nk;
  const int k0 = blockIdx.x * chunk;
  const int k1 = (k0 + chunk < N) ? (k0 + chunk) : N;

  float acc[8][8];
#pragma unroll
  for (int i = 0; i < 8; ++i)
#pragma unroll
    for (int j = 0; j < 8; ++j) acc[i][j] = 0.f;
  float xs[8];
#pragma unroll
  for (int j = 0; j < 8; ++j) xs[j] = 0.f;
  const bool doxs = (blockIdx.z == 0) && (ty == 0);

  for (int k = k0; k < k1; ++k) {
    float4 z0 = *(const float4*)(Z + (size_t)k * 384 + m0);
    float4 z1 = *(const float4*)(Z + (size_t)k * 384 + m0 + 4);
    float4 x0 = *(const float4*)(x + (size_t)k * 256 + d0);
    float4 x1 = *(const float4*)(x + (size_t)k * 256 + d0 + 4);
    float zf[8] = {z0.x, z0.y, z0.z, z0.w, z1.x, z1.y, z1.z, z1.w};
    float xf[8] = {x0.x, x0.y, x0.z, x0.w, x1.x, x1.y, x1.z, x1.w};
#pragma unroll
    for (int i = 0; i < 8; ++i)
#pragma unroll
      for (int j = 0; j < 8; ++j) acc[i][j] = fmaf(zf[i], xf[j], acc[i][j]);
    if (doxs) {
#pragma unroll
      for (int j = 0; j < 8; ++j) xs[j] += xf[j];
    }
  }
#pragma unroll
  for (int i = 0; i < 8; ++i)
#pragma unroll
    for (int j = 0; j < 8; ++j)
      atomicAdd(&Gbuf[(size_t)(m0 + i) * 256 + (d0 + j)], acc[i][j]);
  if (doxs) {
#pragma unroll
    for (int j = 0; j < 8; ++j) atomicAdd(&xsum[d0 + j], xs[j]);
  }
}

// ---------------------------------------------------------------------------
// K2: ZXT[d][cl] = coeff*( sum_i zcw[c][i]*G[i*128+l][d] + zcb[c]*xsum[d] )
// ---------------------------------------------------------------------------
__global__ __launch_bounds__(256) void k_zxt(
    const float* __restrict__ Gbuf, const float* __restrict__ xsum,
    const float* __restrict__ zcw, const float* __restrict__ zcb,
    u16* __restrict__ ZXT, float coeff)
{
  const int cl = blockIdx.x;
  const int d = threadIdx.x;
  const int c = cl >> 7, l = cl & 127;
  float v = zcb[c] * xsum[d];
#pragma unroll
  for (int i = 0; i < 3; ++i)
    v += zcw[c * 3 + i] * Gbuf[(size_t)(i * 128 + l) * 256 + d];
  ZXT[(size_t)d * 384 + cl] = f2bf(coeff * v);
}

// ---------------------------------------------------------------------------
// K_rxz: rxz[e][12] = (1/L) Zi Zj^T (9 dots, stride-12 padded, f32)
// wave per edge, float2 loads, butterfly reduce.
// ---------------------------------------------------------------------------
__global__ __launch_bounds__(256) void k_rxz(
    const float* __restrict__ Z, const int* __restrict__ tei, int E,
    float* __restrict__ rxz)
{
  const int lane = threadIdx.x & 63, wid = threadIdx.x >> 6;
  const int e = blockIdx.x * 4 + wid;
  const int si = tei[e], dj = tei[E + e];
  const float2* pi = (const float2*)(Z + (size_t)si * 384);
  const float2* pj = (const float2*)(Z + (size_t)dj * 384);
  float2 a[3], b[3];
#pragma unroll
  for (int c = 0; c < 3; ++c) {
    a[c] = pi[c * 64 + lane];
    b[c] = pj[c * 64 + lane];
  }
  float d[9];
#pragma unroll
  for (int c = 0; c < 3; ++c)
#pragma unroll
    for (int cc = 0; cc < 3; ++cc)
      d[c * 3 + cc] = fmaf(a[c].x, b[cc].x, a[c].y * b[cc].y);
#pragma unroll
  for (int m = 1; m < 64; m <<= 1) {
#pragma unroll
    for (int k = 0; k < 9; ++k) d[k] += __shfl_xor(d[k], m, 64);
  }
  if (lane == 0) {
    const float s = 1.f / 128.f;
    float4 v0 = {d[0] * s, d[1] * s, d[2] * s, d[3] * s};
    float4 v1 = {d[4] * s, d[5] * s, d[6] * s, d[7] * s};
    float4 v2 = {d[8] * s, 0.f, 0.f, 0.f};
    float4* out = (float4*)(rxz + (size_t)e * 12);
    out[0] = v0; out[1] = v1; out[2] = v2;
  }
}

// ---------------------------------------------------------------------------
// K3: xij branch. 32 edges/block. p=xi*xj -> GEMM1(256, silu) -> GEMM2(768)
//     -> LN -> prod = xij
// ---------------------------------------------------------------------------
__global__ __launch_bounds__(256) void k_xij(
    const float* __restrict__ x, const int* __restrict__ tei, int E,
    const u16* __restrict__ w1, const float* __restrict__ b1,
    const u16* __restrict__ w2, const float* __restrict__ b2,
    const float* __restrict__ lng, const float* __restrict__ lnb,
    u16* __restrict__ prod)
{
  __shared__ __align__(16) u16 pl[32 * 264];
  __shared__ __align__(16) u16 hl[32 * 264];
  __shared__ float sArr[4][32], ssArr[4][32];
  __shared__ int sidx[64];
  const int tid = threadIdx.x;
  const int lane = tid & 63, wid = tid >> 6;
  const int col = lane & 15, qd = lane >> 4;
  const int e0 = blockIdx.x * 32;

  if (tid < 32) sidx[tid] = tei[e0 + tid];
  else if (tid < 64) sidx[tid] = tei[E + e0 + (tid - 32)];
  __syncthreads();

  for (int e = wid; e < 32; e += 4) {
    float4 va = ((const float4*)(x + (size_t)sidx[e] * 256))[lane];
    float4 vb = ((const float4*)(x + (size_t)sidx[32 + e] * 256))[lane];
    u16x4 pv;
    pv[0] = f2bf(va.x * vb.x);
    pv[1] = f2bf(va.y * vb.y);
    pv[2] = f2bf(va.z * vb.z);
    pv[3] = f2bf(va.w * vb.w);
    *(u16x4*)(pl + e * 264 + lane * 4) = pv;
  }
  __syncthreads();

  { // GEMM1
    f32x4 acc1[2][4];
#pragma unroll
    for (int mf = 0; mf < 2; ++mf)
#pragma unroll
      for (int nf = 0; nf < 4; ++nf) acc1[mf][nf] = (f32x4){0.f, 0.f, 0.f, 0.f};
    const int oo = wid * 64;
    for (int kk = 0; kk < 256; kk += 32) {
      bf16x8 a0 = *(const bf16x8*)(pl + col * 264 + kk + qd * 8);
      bf16x8 a1 = *(const bf16x8*)(pl + (16 + col) * 264 + kk + qd * 8);
#pragma unroll
      for (int nf = 0; nf < 4; ++nf) {
        bf16x8 bv = *(const bf16x8*)(w1 + (size_t)(oo + nf * 16 + col) * 256 + kk + qd * 8);
        acc1[0][nf] = mfma16(a0, bv, acc1[0][nf]);
        acc1[1][nf] = mfma16(a1, bv, acc1[1][nf]);
      }
    }
#pragma unroll
    for (int nf = 0; nf < 4; ++nf) {
      const int o = oo + nf * 16 + col;
      const float bias = b1[o];
#pragma unroll
      for (int mf = 0; mf < 2; ++mf)
#pragma unroll
        for (int j = 0; j < 4; ++j)
          hl[(mf * 16 + qd * 4 + j) * 264 + o] = f2bf(siluf(acc1[mf][nf][j] + bias));
    }
  }
  __syncthreads();

  f32x4 acc[2][12];
#pragma unroll
  for (int mf = 0; mf < 2; ++mf)
#pragma unroll
    for (int nf = 0; nf < 12; ++nf) acc[mf][nf] = (f32x4){0.f, 0.f, 0.f, 0.f};
  const int o0 = wid * 192;
  for (int kk = 0; kk < 256; kk += 32) {
    bf16x8 a0 = *(const bf16x8*)(hl + col * 264 + kk + qd * 8);
    bf16x8 a1 = *(const bf16x8*)(hl + (16 + col) * 264 + kk + qd * 8);
#pragma unroll
    for (int nf = 0; nf < 12; ++nf) {
      bf16x8 bv = *(const bf16x8*)(w2 + (size_t)(o0 + nf * 16 + col) * 256 + kk + qd * 8);
      acc[0][nf] = mfma16(a0, bv, acc[0][nf]);
      acc[1][nf] = mfma16(a1, bv, acc[1][nf]);
    }
  }
#pragma unroll
  for (int nf = 0; nf < 12; ++nf) {
    const float bias = b2[o0 + nf * 16 + col];
#pragma unroll
    for (int mf = 0; mf < 2; ++mf)
#pragma unroll
      for (int j = 0; j < 4; ++j) acc[mf][nf][j] += bias;
  }
  float s[2][4], ss[2][4];
#pragma unroll
  for (int mf = 0; mf < 2; ++mf)
#pragma unroll
    for (int j = 0; j < 4; ++j) {
      float a = 0.f, b = 0.f;
#pragma unroll
      for (int nf = 0; nf < 12; ++nf) { float v = acc[mf][nf][j]; a += v; b += v * v; }
      s[mf][j] = a; ss[mf][j] = b;
    }
#pragma unroll
  for (int m = 1; m < 16; m <<= 1) {
#pragma unroll
    for (int mf = 0; mf < 2; ++mf)
#pragma unroll
      for (int j = 0; j < 4; ++j) {
        s[mf][j] += __shfl_xor(s[mf][j], m, 16);
        ss[mf][j] += __shfl_xor(ss[mf][j], m, 16);
      }
  }
  if (col == 0) {
#pragma unroll
    for (int mf = 0; mf < 2; ++mf)
#pragma unroll
      for (int j = 0; j < 4; ++j) {
        sArr[wid][mf * 16 + qd * 4 + j] = s[mf][j];
        ssArr[wid][mf * 16 + qd * 4 + j] = ss[mf][j];
      }
  }
  __syncthreads();
  float mean[2][4], rstd[2][4];
#pragma unroll
  for (int mf = 0; mf < 2; ++mf)
#pragma unroll
    for (int j = 0; j < 4; ++j) {
      const int e = mf * 16 + qd * 4 + j;
      float S = sArr[0][e] + sArr[1][e] + sArr[2][e] + sArr[3][e];
      float SS = ssArr[0][e] + ssArr[1][e] + ssArr[2][e] + ssArr[3][e];
      float mu = S * (1.f / 768.f);
      float var = fmaxf(SS * (1.f / 768.f) - mu * mu, 0.f);
      mean[mf][j] = mu;
      rstd[mf][j] = rsqrtf(var + 1e-5f);
    }
#pragma unroll
  for (int nf = 0; nf < 12; ++nf) {
    const int o = o0 + nf * 16 + col;
    const float gv = lng[o], bv = lnb[o];
#pragma unroll
    for (int mf = 0; mf < 2; ++mf)
#pragma unroll
      for (int j = 0; j < 4; ++j) {
        const int e = mf * 16 + qd * 4 + j;
        float v = (acc[mf][nf][j] - mean[mf][j]) * rstd[mf][j] * gv + bv;
        prod[(size_t)(e0 + e) * 768 + o] = f2bf(v);
      }
  }
}

// ---------------------------------------------------------------------------
// K4: xz branch v2. 16 edges/block, rows 0..15 = side A, 16..31 = side B.
// rxz (precomputed) -> MFMA GEMM1 (K=32, bias folded) -> silu -> g1s
// -> GEMM2 (768) -> silu -> LN -> prod *= (A+B)
// ---------------------------------------------------------------------------
__global__ __launch_bounds__(256) void k_xz2(
    const float* __restrict__ rxz, int E,
    const u16* __restrict__ w1e,      // [256][32] bf16, bias at k=9
    const u16* __restrict__ zw2,      // [768][256] bf16
    const float* __restrict__ zb2,
    const float* __restrict__ lng, const float* __restrict__ lnb,
    u16* __restrict__ prod)
{
  __shared__ __align__(16) float rs[16 * 12];
  __shared__ __align__(16) u16 ax[32 * 32];
  __shared__ __align__(16) u16 g1s[32 * 264];
  __shared__ float sArr[4][32], ssArr[4][32];
  const int tid = threadIdx.x;
  const int lane = tid & 63, wid = tid >> 6;
  const int col = lane & 15, qd = lane >> 4;
  const int e0 = blockIdx.x * 16;

  if (tid < 48)
    ((float4*)rs)[tid] = ((const float4*)(rxz + (size_t)e0 * 12))[tid];
  __syncthreads();

  if (tid < 128) {  // build A-matrix [32 rows][32 k] bf16 (B rows transposed)
    const int r = tid & 31, kq = tid >> 5;  // kq 0..3
    const int side = r >> 4, e = r & 15;
    u16 w[8];
#pragma unroll
    for (int t = 0; t < 8; ++t) {
      const int k = kq * 8 + t;
      float v;
      if (k < 9) {
        const int c = k / 3, cc = k % 3;
        const int pp = side ? (cc * 3 + c) : k;
        v = rs[e * 12 + pp];
      } else v = (k == 9) ? 1.f : 0.f;
      w[t] = f2bf(v);
    }
    *(u16x4*)(ax + r * 32 + kq * 8) = *(u16x4*)w;
    *(u16x4*)(ax + r * 32 + kq * 8 + 4) = *(u16x4*)(w + 4);
  }
  __syncthreads();

  { // GEMM1: C[32][256] = ax @ w1e^T, per-wave o-range 64, single K-iter
    f32x4 c1[2][4];
#pragma unroll
    for (int mf = 0; mf < 2; ++mf)
#pragma unroll
      for (int nf = 0; nf < 4; ++nf) c1[mf][nf] = (f32x4){0.f, 0.f, 0.f, 0.f};
    const int oo = wid * 64;
    bf16x8 a0 = *(const bf16x8*)(ax + (size_t)col * 32 + qd * 8);
    bf16x8 a1 = *(const bf16x8*)(ax + (size_t)(16 + col) * 32 + qd * 8);
#pragma unroll
    for (int nf = 0; nf < 4; ++nf) {
      bf16x8 bv = *(const bf16x8*)(w1e + (size_t)(oo + nf * 16 + col) * 32 + qd * 8);
      c1[0][nf] = mfma16(a0, bv, c1[0][nf]);
      c1[1][nf] = mfma16(a1, bv, c1[1][nf]);
    }
#pragma unroll
    for (int nf = 0; nf < 4; ++nf) {
      const int o = oo + nf * 16 + col;
#pragma unroll
      for (int mf = 0; mf < 2; ++mf)
#pragma unroll
        for (int j = 0; j < 4; ++j)
          g1s[(mf * 16 + qd * 4 + j) * 264 + o] = f2bf(siluf(c1[mf][nf][j]));
    }
  }
  __syncthreads();

  // GEMM2: C[32][768], per-wave o-range 192
  f32x4 acc[2][12];
#pragma unroll
  for (int mf = 0; mf < 2; ++mf)
#pragma unroll
    for (int nf = 0; nf < 12; ++nf) acc[mf][nf] = (f32x4){0.f, 0.f, 0.f, 0.f};
  const int o0 = wid * 192;
  for (int kk = 0; kk < 256; kk += 32) {
    bf16x8 a0 = *(const bf16x8*)(g1s + col * 264 + kk + qd * 8);
    bf16x8 a1 = *(const bf16x8*)(g1s + (16 + col) * 264 + kk + qd * 8);
#pragma unroll
    for (int nf = 0; nf < 12; ++nf) {
      bf16x8 bv = *(const bf16x8*)(zw2 + (size_t)(o0 + nf * 16 + col) * 256 + kk + qd * 8);
      acc[0][nf] = mfma16(a0, bv, acc[0][nf]);
      acc[1][nf] = mfma16(a1, bv, acc[1][nf]);
    }
  }
  // second SiLU of zlin, then LN stats
#pragma unroll
  for (int nf = 0; nf < 12; ++nf) {
    const float bias = zb2[o0 + nf * 16 + col];
#pragma unroll
    for (int mf = 0; mf < 2; ++mf)
#pragma unroll
      for (int j = 0; j < 4; ++j) acc[mf][nf][j] = siluf(acc[mf][nf][j] + bias);
  }
  float s[2][4], ss[2][4];
#pragma unroll
  for (int mf = 0; mf < 2; ++mf)
#pragma unroll
    for (int j = 0; j < 4; ++j) {
      float a = 0.f, b = 0.f;
#pragma unroll
      for (int nf = 0; nf < 12; ++nf) { float v = acc[mf][nf][j]; a += v; b += v * v; }
      s[mf][j] = a; ss[mf][j] = b;
    }
#pragma unroll
  for (int m = 1; m < 16; m <<= 1) {
#pragma unroll
    for (int mf = 0; mf < 2; ++mf)
#pragma unroll
      for (int j = 0; j < 4; ++j) {
        s[mf][j] += __shfl_xor(s[mf][j], m, 16);
        ss[mf][j] += __shfl_xor(ss[mf][j], m, 16);
      }
  }
  if (col == 0) {
#pragma unroll
    for (int mf = 0; mf < 2; ++mf)
#pragma unroll
      for (int j = 0; j < 4; ++j) {
        sArr[wid][mf * 16 + qd * 4 + j] = s[mf][j];
        ssArr[wid][mf * 16 + qd * 4 + j] = ss[mf][j];
      }
  }
  __syncthreads();
  float mean[2][4], rstd[2][4];
#pragma unroll
  for (int mf = 0; mf < 2; ++mf)
#pragma unroll
    for (int j = 0; j < 4; ++j) {
      const int r = mf * 16 + qd * 4 + j;
      float S = sArr[0][r] + sArr[1][r] + sArr[2][r] + sArr[3][r];
      float SS = ssArr[0][r] + ssArr[1][r] + ssArr[2][r] + ssArr[3][r];
      float mu = S * (1.f / 768.f);
      mean[mf][j] = mu;
      rstd[mf][j] = rsqrtf(fmaxf(SS * (1.f / 768.f) - mu * mu, 0.f) + 1e-5f);
    }
#pragma unroll
  for (int nf = 0; nf < 12; ++nf) {
    const int o = o0 + nf * 16 + col;
    const float gv = lng[o], bv = lnb[o];
#pragma unroll
    for (int j = 0; j < 4; ++j) {
      const int e = qd * 4 + j;
      float va = (acc[0][nf][j] - mean[0][j]) * rstd[0][j] * gv + bv;
      float vb = (acc[1][nf][j] - mean[1][j]) * rstd[1][j] * gv + bv;
      const size_t ix = (size_t)(e0 + e) * 768 + o;
      prod[ix] = f2bf(bf2f(prod[ix]) * (va + vb));
    }
  }
}

// ---------------------------------------------------------------------------
// K5: t = (Zi*Zj) @ ZXT^T -> xzx = LN(t @ zxw^T + zxb) -> out
// ---------------------------------------------------------------------------
__global__ __launch_bounds__(256) void k_final(
    const float* __restrict__ Z, const int* __restrict__ tei, int E,
    const u16* __restrict__ ZXT,
    const u16* __restrict__ zxw, const float* __restrict__ zxb,
    const float* __restrict__ lng, const float* __restrict__ lnb,
    const u16* __restrict__ prod,
    const float* __restrict__ lw, const float* __restrict__ lb,
    float* __restrict__ out)
{
  __shared__ __align__(16) u16 ql[32 * 392];
  __shared__ __align__(16) u16 tl[32 * 264];
  __shared__ float sArr[4][32], ssArr[4][32], oArr[4][32];
  __shared__ int sidx[64];
  const int tid = threadIdx.x;
  const int lane = tid & 63, wid = tid >> 6;
  const int col = lane & 15, qd = lane >> 4;
  const int e0 = blockIdx.x * 32;

  if (tid < 32) sidx[tid] = tei[e0 + tid];
  else if (tid < 64) sidx[tid] = tei[E + e0 + (tid - 32)];
  __syncthreads();

  for (int e = wid; e < 32; e += 4) {
    const float2* zi = (const float2*)(Z + (size_t)sidx[e] * 384);
    const float2* zj = (const float2*)(Z + (size_t)sidx[32 + e] * 384);
    u16x2* qp = (u16x2*)(ql + e * 392);
#pragma unroll
    for (int p = 0; p < 3; ++p) {
      float2 a = zi[p * 64 + lane], b = zj[p * 64 + lane];
      u16x2 r;
      r[0] = f2bf(a.x * b.x);
      r[1] = f2bf(a.y * b.y);
      qp[p * 64 + lane] = r;
    }
  }
  __syncthreads();

  { // t-GEMM: N=256 (d), K=384
    f32x4 acc1[2][4];
#pragma unroll
    for (int mf = 0; mf < 2; ++mf)
#pragma unroll
      for (int nf = 0; nf < 4; ++nf) acc1[mf][nf] = (f32x4){0.f, 0.f, 0.f, 0.f};
    const int oo = wid * 64;
    for (int kk = 0; kk < 384; kk += 32) {
      bf16x8 a0 = *(const bf16x8*)(ql + col * 392 + kk + qd * 8);
      bf16x8 a1 = *(const bf16x8*)(ql + (16 + col) * 392 + kk + qd * 8);
#pragma unroll
      for (int nf = 0; nf < 4; ++nf) {
        bf16x8 bv = *(const bf16x8*)(ZXT + (size_t)(oo + nf * 16 + col) * 384 + kk + qd * 8);
        acc1[0][nf] = mfma16(a0, bv, acc1[0][nf]);
        acc1[1][nf] = mfma16(a1, bv, acc1[1][nf]);
      }
    }
#pragma unroll
    for (int nf = 0; nf < 4; ++nf) {
      const int o = oo + nf * 16 + col;
#pragma unroll
      for (int mf = 0; mf < 2; ++mf)
#pragma unroll
        for (int j = 0; j < 4; ++j)
          tl[(mf * 16 + qd * 4 + j) * 264 + o] = f2bf(acc1[mf][nf][j]);
    }
  }
  __syncthreads();

  f32x4 acc[2][12];
#pragma unroll
  for (int mf = 0; mf < 2; ++mf)
#pragma unroll
    for (int nf = 0; nf < 12; ++nf) acc[mf][nf] = (f32x4){0.f, 0.f, 0.f, 0.f};
  const int o0 = wid * 192;
  for (int kk = 0; kk < 256; kk += 32) {
    bf16x8 a0 = *(const bf16x8*)(tl + col * 264 + kk + qd * 8);
    bf16x8 a1 = *(const bf16x8*)(tl + (16 + col) * 264 + kk + qd * 8);
#pragma unroll
    for (int nf = 0; nf < 12; ++nf) {
      bf16x8 bv = *(const bf16x8*)(zxw + (size_t)(o0 + nf * 16 + col) * 256 + kk + qd * 8);
      acc[0][nf] = mfma16(a0, bv, acc[0][nf]);
      acc[1][nf] = mfma16(a1, bv, acc[1][nf]);
    }
  }
#pragma unroll
  for (int nf = 0; nf < 12; ++nf) {
    const float bias = zxb[o0 + nf * 16 + col];
#pragma unroll
    for (int mf = 0; mf < 2; ++mf)
#pragma unroll
      for (int j = 0; j < 4; ++j) acc[mf][nf][j] += bias;
  }
  float s[2][4], ss[2][4];
#pragma unroll
  for (int mf = 0; mf < 2; ++mf)
#pragma unroll
    for (int j = 0; j < 4; ++j) {
      float a = 0.f, b = 0.f;
#pragma unroll
      for (int nf = 0; nf < 12; ++nf) { float v = acc[mf][nf][j]; a += v; b += v * v; }
      s[mf][j] = a; ss[mf][j] = b;
    }
#pragma unroll
  for (int m = 1; m < 16; m <<= 1) {
#pragma unroll
    for (int mf = 0; mf < 2; ++mf)
#pragma unroll
      for (int j = 0; j < 4; ++j) {
        s[mf][j] += __shfl_xor(s[mf][j], m, 16);
        ss[mf][j] += __shfl_xor(ss[mf][j], m, 16);
      }
  }
  if (col == 0) {
#pragma unroll
    for (int mf = 0; mf < 2; ++mf)
#pragma unroll
      for (int j = 0; j < 4; ++j) {
        sArr[wid][mf * 16 + qd * 4 + j] = s[mf][j];
        ssArr[wid][mf * 16 + qd * 4 + j] = ss[mf][j];
      }
  }
  __syncthreads();
  float mean[2][4], rstd[2][4];
#pragma unroll
  for (int mf = 0; mf < 2; ++mf)
#pragma unroll
    for (int j = 0; j < 4; ++j) {
      const int e = mf * 16 + qd * 4 + j;
      float S = sArr[0][e] + sArr[1][e] + sArr[2][e] + sArr[3][e];
      float SS = ssArr[0][e] + ssArr[1][e] + ssArr[2][e] + ssArr[3][e];
      float mu = S * (1.f / 768.f);
      float var = fmaxf(SS * (1.f / 768.f) - mu * mu, 0.f);
      mean[mf][j] = mu;
      rstd[mf][j] = rsqrtf(var + 1e-5f);
    }
  float pacc[2][4];
#pragma unroll
  for (int mf = 0; mf < 2; ++mf)
#pragma unroll
    for (int j = 0; j < 4; ++j) pacc[mf][j] = 0.f;
#pragma unroll
  for (int nf = 0; nf < 12; ++nf) {
    const int o = o0 + nf * 16 + col;
    const float gv = lng[o], bvq = lnb[o], lwv = lw[o];
#pragma unroll
    for (int mf = 0; mf < 2; ++mf)
#pragma unroll
      for (int j = 0; j < 4; ++j) {
        const int e = mf * 16 + qd * 4 + j;
        float xv = (acc[mf][nf][j] - mean[mf][j]) * rstd[mf][j] * gv + bvq;
        pacc[mf][j] += bf2f(prod[(size_t)(e0 + e) * 768 + o]) * xv * lwv;
      }
  }
#pragma unroll
  for (int m = 1; m < 16; m <<= 1) {
#pragma unroll
    for (int mf = 0; mf < 2; ++mf)
#pragma unroll
      for (int j = 0; j < 4; ++j) pacc[mf][j] += __shfl_xor(pacc[mf][j], m, 16);
  }
  if (col == 0) {
#pragma unroll
    for (int mf = 0; mf < 2; ++mf)
#pragma unroll
      for (int j = 0; j < 4; ++j) oArr[wid][mf * 16 + qd * 4 + j] = pacc[mf][j];
  }
  __syncthreads();
  if (tid < 32) {
    out[e0 + tid] = oArr[0][tid] + oArr[1][tid] + oArr[2][tid] + oArr[3][tid] + lb[0];
  }
}

// ---------------------------------------------------------------------------
extern "C" void kernel_launch(void* const* d_in, const int* in_sizes, int n_in,
                              void* d_out, int out_size, void* d_ws, size_t ws_size,
                              hipStream_t stream)
{
  const float* x    = (const float*)d_in[0];
  const float* Z    = (const float*)d_in[1];
  const int*   tei  = (const int*)d_in[3];
  const float* xw1  = (const float*)d_in[4];
  const float* xb1  = (const float*)d_in[5];
  const float* xw2  = (const float*)d_in[6];
  const float* xb2  = (const float*)d_in[7];
  const float* xlg  = (const float*)d_in[8];
  const float* xlb  = (const float*)d_in[9];
  const float* zw1  = (const float*)d_in[10];
  const float* zb1  = (const float*)d_in[11];
  const float* zw2  = (const float*)d_in[12];
  const float* zb2  = (const float*)d_in[13];
  const float* zlg  = (const float*)d_in[14];
  const float* zlb  = (const float*)d_in[15];
  const float* zcw  = (const float*)d_in[16];
  const float* zcb  = (const float*)d_in[17];
  const float* zxw  = (const float*)d_in[18];
  const float* zxb  = (const float*)d_in[19];
  const float* zxlg = (const float*)d_in[20];
  const float* zxlb = (const float*)d_in[21];
  const float* lw   = (const float*)d_in[22];
  const float* lb   = (const float*)d_in[23];

  const int N = in_sizes[0] / 256;
  const int E = in_sizes[3] / 2;
  if (E <= 0) return;

  char* ws = (char*)d_ws;
  u16* prod = (u16*)ws;                       // E*768 bf16
  size_t off = (size_t)E * 768 * sizeof(u16);
  float* Gbuf = (float*)(ws + off);           // 384*256 f32
  off += (size_t)384 * 256 * sizeof(float);
  float* xsum = (float*)(ws + off);           // 256 f32
  off += 256 * sizeof(float);
  u16* ZXT = (u16*)(ws + off);                // 256*384 bf16
  off += (size_t)256 * 384 * sizeof(u16);
  u16* xw1b = (u16*)(ws + off); off += (size_t)65536 * sizeof(u16);
  u16* xw2b = (u16*)(ws + off); off += (size_t)196608 * sizeof(u16);
  u16* zw2b = (u16*)(ws + off); off += (size_t)196608 * sizeof(u16);
  u16* zxwb = (u16*)(ws + off); off += (size_t)196608 * sizeof(u16);
  u16* w1e  = (u16*)(ws + off); off += (size_t)256 * 32 * sizeof(u16);
  float* rxz = (float*)(ws + off); off += (size_t)E * 12 * sizeof(float);

  hipMemsetAsync(Gbuf, 0, (size_t)384 * 256 * sizeof(float) + 256 * sizeof(float), stream);

  k_f2bf<<<dim3(65536 / 256), 256, 0, stream>>>(xw1, xw1b, 65536);
  k_f2bf<<<dim3(196608 / 256), 256, 0, stream>>>(xw2, xw2b, 196608);
  k_f2bf<<<dim3(196608 / 256), 256, 0, stream>>>(zw2, zw2b, 196608);
  k_f2bf<<<dim3(196608 / 256), 256, 0, stream>>>(zxw, zxwb, 196608);
  k_w1e<<<dim3(1), 256, 0, stream>>>(zw1, zb1, w1e);

  const float coeff = 1.f / (sqrtf((float)N) * 3840.f);

  k_greduce<<<dim3(128, 2, 3), 256, 0, stream>>>(x, Z, Gbuf, xsum, N);
  k_zxt<<<dim3(384), 256, 0, stream>>>(Gbuf, xsum, zcw, zcb, ZXT, coeff);
  k_rxz<<<dim3(E / 4), 256, 0, stream>>>(Z, tei, E, rxz);
  k_xij<<<dim3(E / 32), 256, 0, stream>>>(x, tei, E, xw1b, xb1, xw2b, xb2, xlg, xlb, prod);
  k_xz2<<<dim3(E / 16), 256, 0, stream>>>(rxz, E, w1e, zw2b, zb2, zlg, zlb, prod);
  k_final<<<dim3(E / 32), 256, 0, stream>>>(Z, tei, E, ZXT, zxwb, zxb, zxlg, zxlb, prod, lw, lb, (float*)d_out);
}

// Round 4
// 2141.110 us; speedup vs baseline: 1.4103x; 1.3449x over previous
//
#include <hip/hip_runtime.h>
#include <math.h>

typedef unsigned short u16;
typedef __attribute__((ext_vector_type(8))) short bf16x8;
typedef __attribute__((ext_vector_type(4))) float f32x4;
typedef __attribute__((ext_vector_type(2))) unsigned short u16x2;
typedef __attribute__((ext_vector_type(4))) unsigned short u16x4;
typedef __attribute__((ext_vector_type(8))) unsigned short u16x8;

#define DEV static __device__ __forceinline__
#define KP 100352   // 100000 padded to 98*1024

DEV float bf2f(u16 h) {
  union { unsigned int u; float f; } v; v.u = ((unsigned int)h) << 16; return v.f;
}
DEV u16 f2bf(float f) {
  union { float f; unsigned int u; } v; v.f = f;
  return (u16)((v.u + 0x7FFFu + ((v.u >> 16) & 1u)) >> 16);
}
DEV float siluf(float x) { return x / (1.f + __expf(-x)); }
DEV f32x4 mfma16(bf16x8 a, bf16x8 b, f32x4 c) {
  return __builtin_amdgcn_mfma_f32_16x16x32_bf16(a, b, c, 0, 0, 0);
}

// ---------------------------------------------------------------------------
__global__ __launch_bounds__(256) void k_f2bf(const float* __restrict__ s,
                                              u16* __restrict__ d, int n) {
  int i = blockIdx.x * 256 + threadIdx.x;
  if (i < n) d[i] = f2bf(s[i]);
}

__global__ __launch_bounds__(256) void k_w1e(const float* __restrict__ zw1,
                                             const float* __restrict__ zb1,
                                             u16* __restrict__ w1e) {
  const int o = threadIdx.x;
#pragma unroll
  for (int k = 0; k < 32; ++k) {
    float v = (k < 9) ? zw1[o * 9 + k] : ((k == 9) ? zb1[o] : 0.f);
    w1e[o * 32 + k] = f2bf(v);
  }
}

// ---------------------------------------------------------------------------
// K_tr: transpose f32 [100000][C] -> bf16 [C][KP] (zero-padded rows >= 100000)
// ---------------------------------------------------------------------------
__global__ __launch_bounds__(256) void k_tr(const float* __restrict__ in,
                                            u16* __restrict__ out, int C) {
  __shared__ float tile[64][65];
  const int k0 = blockIdx.x * 64;
  const int n0 = blockIdx.y * 64;
  const int tid = threadIdx.x;
  const int r = tid >> 4, c4 = (tid & 15) * 4;
#pragma unroll
  for (int rr = 0; rr < 4; ++rr) {
    const int row = r + rr * 16;
    const int k = k0 + row;
    float4 v = (k < 100000) ? *(const float4*)(in + (size_t)k * C + n0 + c4)
                            : (float4){0.f, 0.f, 0.f, 0.f};
    tile[row][c4] = v.x; tile[row][c4 + 1] = v.y;
    tile[row][c4 + 2] = v.z; tile[row][c4 + 3] = v.w;
  }
  __syncthreads();
  const int n = tid >> 2, kq = (tid & 3) * 16;
  u16 buf[16];
#pragma unroll
  for (int i = 0; i < 16; ++i) buf[i] = f2bf(tile[kq + i][n]);
  u16* dst = out + (size_t)(n0 + n) * KP + k0 + kq;
  *(u16x8*)dst = *(u16x8*)buf;
  *(u16x8*)(dst + 8) = *(u16x8*)(buf + 8);
}

// ---------------------------------------------------------------------------
// K_mmzx: P[s][m][d] = sum_{k in chunk s} Zt[m][k] * xt[d][k]
// grid (2 dt, 3 mt, 98 s), block 256 = 4 waves, wave = 32m x 128d, no LDS.
// ---------------------------------------------------------------------------
__global__ __launch_bounds__(256) void k_mmzx(
    const u16* __restrict__ Zt, const u16* __restrict__ xt,
    float* __restrict__ Pbuf)
{
  const int dt = blockIdx.x, mt = blockIdx.y, s = blockIdx.z;
  const int lane = threadIdx.x & 63, wid = threadIdx.x >> 6;
  const int col = lane & 15, qd = lane >> 4;
  const int m0 = mt * 128 + wid * 32;
  const int d0 = dt * 128;
  const size_t kc = (size_t)s * 1024;

  f32x4 acc[2][8];
#pragma unroll
  for (int mf = 0; mf < 2; ++mf)
#pragma unroll
    for (int nf = 0; nf < 8; ++nf) acc[mf][nf] = (f32x4){0.f, 0.f, 0.f, 0.f};

  const u16* za = Zt + (size_t)(m0 + col) * KP + kc + qd * 8;
  const u16* zb = Zt + (size_t)(m0 + 16 + col) * KP + kc + qd * 8;
  const u16* xb = xt + (size_t)(d0 + col) * KP + kc + qd * 8;

  for (int kk = 0; kk < 1024; kk += 32) {
    bf16x8 a0 = *(const bf16x8*)(za + kk);
    bf16x8 a1 = *(const bf16x8*)(zb + kk);
#pragma unroll
    for (int nf = 0; nf < 8; ++nf) {
      bf16x8 bv = *(const bf16x8*)(xb + (size_t)nf * 16 * KP + kk);
      acc[0][nf] = mfma16(a0, bv, acc[0][nf]);
      acc[1][nf] = mfma16(a1, bv, acc[1][nf]);
    }
  }
  float* P = Pbuf + (size_t)s * 98304;
#pragma unroll
  for (int mf = 0; mf < 2; ++mf)
#pragma unroll
    for (int nf = 0; nf < 8; ++nf)
#pragma unroll
      for (int j = 0; j < 4; ++j)
        P[(size_t)(m0 + mf * 16 + qd * 4 + j) * 256 + d0 + nf * 16 + col] =
            acc[mf][nf][j];
}

// ---------------------------------------------------------------------------
__global__ __launch_bounds__(256) void k_redG(const float* __restrict__ P,
                                              float* __restrict__ G) {
  const int m = blockIdx.x, d = threadIdx.x;
  float s = 0.f;
  for (int sp = 0; sp < 98; ++sp) s += P[(size_t)sp * 98304 + m * 256 + d];
  G[m * 256 + d] = s;
}

__global__ __launch_bounds__(256) void k_xsum(const float* __restrict__ x,
                                              float* __restrict__ xsum, int N) {
  const int nb = gridDim.x;
  const int chunk = (N + nb - 1) / nb;
  const int k0 = blockIdx.x * chunk;
  const int k1 = (k0 + chunk < N) ? (k0 + chunk) : N;
  float s = 0.f;
  for (int k = k0; k < k1; ++k) s += x[(size_t)k * 256 + threadIdx.x];
  atomicAdd(&xsum[threadIdx.x], s);
}

// ---------------------------------------------------------------------------
__global__ __launch_bounds__(256) void k_zxt(
    const float* __restrict__ Gbuf, const float* __restrict__ xsum,
    const float* __restrict__ zcw, const float* __restrict__ zcb,
    u16* __restrict__ ZXT, float coeff)
{
  const int cl = blockIdx.x;
  const int d = threadIdx.x;
  const int c = cl >> 7, l = cl & 127;
  float v = zcb[c] * xsum[d];
#pragma unroll
  for (int i = 0; i < 3; ++i)
    v += zcw[c * 3 + i] * Gbuf[(size_t)(i * 128 + l) * 256 + d];
  ZXT[(size_t)d * 384 + cl] = f2bf(coeff * v);
}

// ---------------------------------------------------------------------------
__global__ __launch_bounds__(256) void k_rxz(
    const float* __restrict__ Z, const int* __restrict__ tei, int E,
    float* __restrict__ rxz)
{
  const int lane = threadIdx.x & 63, wid = threadIdx.x >> 6;
  const int e = blockIdx.x * 4 + wid;
  const int si = tei[e], dj = tei[E + e];
  const float2* pi = (const float2*)(Z + (size_t)si * 384);
  const float2* pj = (const float2*)(Z + (size_t)dj * 384);
  float2 a[3], b[3];
#pragma unroll
  for (int c = 0; c < 3; ++c) { a[c] = pi[c * 64 + lane]; b[c] = pj[c * 64 + lane]; }
  float d[9];
#pragma unroll
  for (int c = 0; c < 3; ++c)
#pragma unroll
    for (int cc = 0; cc < 3; ++cc)
      d[c * 3 + cc] = fmaf(a[c].x, b[cc].x, a[c].y * b[cc].y);
#pragma unroll
  for (int m = 1; m < 64; m <<= 1) {
#pragma unroll
    for (int k = 0; k < 9; ++k) d[k] += __shfl_xor(d[k], m, 64);
  }
  if (lane == 0) {
    const float s = 1.f / 128.f;
    float4 v0 = {d[0] * s, d[1] * s, d[2] * s, d[3] * s};
    float4 v1 = {d[4] * s, d[5] * s, d[6] * s, d[7] * s};
    float4 v2 = {d[8] * s, 0.f, 0.f, 0.f};
    float4* out = (float4*)(rxz + (size_t)e * 12);
    out[0] = v0; out[1] = v1; out[2] = v2;
  }
}

// ---------------------------------------------------------------------------
// K_xij: 32 edges/block, 512 threads = 8 waves (o-range 96 in GEMM2)
// ---------------------------------------------------------------------------
__global__ __launch_bounds__(512) void k_xij(
    const float* __restrict__ x, const int* __restrict__ tei, int E,
    const u16* __restrict__ w1, const float* __restrict__ b1,
    const u16* __restrict__ w2, const float* __restrict__ b2,
    const float* __restrict__ lng, const float* __restrict__ lnb,
    u16* __restrict__ prod)
{
  __shared__ __align__(16) u16 pl[32 * 264];
  __shared__ __align__(16) u16 hl[32 * 264];
  __shared__ float sArr[8][32], ssArr[8][32];
  __shared__ int sidx[64];
  const int tid = threadIdx.x;
  const int lane = tid & 63, wid = tid >> 6;
  const int col = lane & 15, qd = lane >> 4;
  const int e0 = blockIdx.x * 32;

  if (tid < 32) sidx[tid] = tei[e0 + tid];
  else if (tid < 64) sidx[tid] = tei[E + e0 + (tid - 32)];
  __syncthreads();

  for (int e = wid; e < 32; e += 8) {
    float4 va = ((const float4*)(x + (size_t)sidx[e] * 256))[lane];
    float4 vb = ((const float4*)(x + (size_t)sidx[32 + e] * 256))[lane];
    u16x4 pv;
    pv[0] = f2bf(va.x * vb.x); pv[1] = f2bf(va.y * vb.y);
    pv[2] = f2bf(va.z * vb.z); pv[3] = f2bf(va.w * vb.w);
    *(u16x4*)(pl + e * 264 + lane * 4) = pv;
  }
  __syncthreads();

  { // GEMM1: o-range 32/wave
    f32x4 acc1[2][2];
#pragma unroll
    for (int mf = 0; mf < 2; ++mf)
#pragma unroll
      for (int nf = 0; nf < 2; ++nf) acc1[mf][nf] = (f32x4){0.f, 0.f, 0.f, 0.f};
    const int oo = wid * 32;
    for (int kk = 0; kk < 256; kk += 32) {
      bf16x8 a0 = *(const bf16x8*)(pl + col * 264 + kk + qd * 8);
      bf16x8 a1 = *(const bf16x8*)(pl + (16 + col) * 264 + kk + qd * 8);
#pragma unroll
      for (int nf = 0; nf < 2; ++nf) {
        bf16x8 bv = *(const bf16x8*)(w1 + (size_t)(oo + nf * 16 + col) * 256 + kk + qd * 8);
        acc1[0][nf] = mfma16(a0, bv, acc1[0][nf]);
        acc1[1][nf] = mfma16(a1, bv, acc1[1][nf]);
      }
    }
#pragma unroll
    for (int nf = 0; nf < 2; ++nf) {
      const int o = oo + nf * 16 + col;
      const float bias = b1[o];
#pragma unroll
      for (int mf = 0; mf < 2; ++mf)
#pragma unroll
        for (int j = 0; j < 4; ++j)
          hl[(mf * 16 + qd * 4 + j) * 264 + o] = f2bf(siluf(acc1[mf][nf][j] + bias));
    }
  }
  __syncthreads();

  // GEMM2: o-range 96/wave
  f32x4 acc[2][6];
#pragma unroll
  for (int mf = 0; mf < 2; ++mf)
#pragma unroll
    for (int nf = 0; nf < 6; ++nf) acc[mf][nf] = (f32x4){0.f, 0.f, 0.f, 0.f};
  const int o0 = wid * 96;
  for (int kk = 0; kk < 256; kk += 32) {
    bf16x8 a0 = *(const bf16x8*)(hl + col * 264 + kk + qd * 8);
    bf16x8 a1 = *(const bf16x8*)(hl + (16 + col) * 264 + kk + qd * 8);
#pragma unroll
    for (int nf = 0; nf < 6; ++nf) {
      bf16x8 bv = *(const bf16x8*)(w2 + (size_t)(o0 + nf * 16 + col) * 256 + kk + qd * 8);
      acc[0][nf] = mfma16(a0, bv, acc[0][nf]);
      acc[1][nf] = mfma16(a1, bv, acc[1][nf]);
    }
  }
#pragma unroll
  for (int nf = 0; nf < 6; ++nf) {
    const float bias = b2[o0 + nf * 16 + col];
#pragma unroll
    for (int mf = 0; mf < 2; ++mf)
#pragma unroll
      for (int j = 0; j < 4; ++j) acc[mf][nf][j] += bias;
  }
  float s[2][4], ss[2][4];
#pragma unroll
  for (int mf = 0; mf < 2; ++mf)
#pragma unroll
    for (int j = 0; j < 4; ++j) {
      float a = 0.f, b = 0.f;
#pragma unroll
      for (int nf = 0; nf < 6; ++nf) { float v = acc[mf][nf][j]; a += v; b += v * v; }
      s[mf][j] = a; ss[mf][j] = b;
    }
#pragma unroll
  for (int m = 1; m < 16; m <<= 1) {
#pragma unroll
    for (int mf = 0; mf < 2; ++mf)
#pragma unroll
      for (int j = 0; j < 4; ++j) {
        s[mf][j] += __shfl_xor(s[mf][j], m, 16);
        ss[mf][j] += __shfl_xor(ss[mf][j], m, 16);
      }
  }
  if (col == 0) {
#pragma unroll
    for (int mf = 0; mf < 2; ++mf)
#pragma unroll
      for (int j = 0; j < 4; ++j) {
        sArr[wid][mf * 16 + qd * 4 + j] = s[mf][j];
        ssArr[wid][mf * 16 + qd * 4 + j] = ss[mf][j];
      }
  }
  __syncthreads();
  float mean[2][4], rstd[2][4];
#pragma unroll
  for (int mf = 0; mf < 2; ++mf)
#pragma unroll
    for (int j = 0; j < 4; ++j) {
      const int e = mf * 16 + qd * 4 + j;
      float S = 0.f, SS = 0.f;
#pragma unroll
      for (int w = 0; w < 8; ++w) { S += sArr[w][e]; SS += ssArr[w][e]; }
      float mu = S * (1.f / 768.f);
      mean[mf][j] = mu;
      rstd[mf][j] = rsqrtf(fmaxf(SS * (1.f / 768.f) - mu * mu, 0.f) + 1e-5f);
    }
#pragma unroll
  for (int nf = 0; nf < 6; ++nf) {
    const int o = o0 + nf * 16 + col;
    const float gv = lng[o], bv = lnb[o];
#pragma unroll
    for (int mf = 0; mf < 2; ++mf)
#pragma unroll
      for (int j = 0; j < 4; ++j) {
        const int e = mf * 16 + qd * 4 + j;
        float v = (acc[mf][nf][j] - mean[mf][j]) * rstd[mf][j] * gv + bv;
        prod[(size_t)(e0 + e) * 768 + o] = f2bf(v);
      }
  }
}

// ---------------------------------------------------------------------------
// K_xz2: 16 edges/block (rows 0-15 side A, 16-31 side B), 512 threads
// ---------------------------------------------------------------------------
__global__ __launch_bounds__(512) void k_xz2(
    const float* __restrict__ rxz, int E,
    const u16* __restrict__ w1e, const u16* __restrict__ zw2,
    const float* __restrict__ zb2,
    const float* __restrict__ lng, const float* __restrict__ lnb,
    u16* __restrict__ prod)
{
  __shared__ __align__(16) float rs[16 * 12];
  __shared__ __align__(16) u16 ax[32 * 32];
  __shared__ __align__(16) u16 g1s[32 * 264];
  __shared__ float sArr[2][8][16], ssArr[2][8][16];
  const int tid = threadIdx.x;
  const int lane = tid & 63, wid = tid >> 6;
  const int col = lane & 15, qd = lane >> 4;
  const int e0 = blockIdx.x * 16;

  if (tid < 48)
    ((float4*)rs)[tid] = ((const float4*)(rxz + (size_t)e0 * 12))[tid];
  __syncthreads();

  if (tid < 128) {
    const int r = tid & 31, kq = tid >> 5;
    const int side = r >> 4, e = r & 15;
    u16 w[8];
#pragma unroll
    for (int t = 0; t < 8; ++t) {
      const int k = kq * 8 + t;
      float v;
      if (k < 9) {
        const int c = k / 3, cc = k % 3;
        const int pp = side ? (cc * 3 + c) : k;
        v = rs[e * 12 + pp];
      } else v = (k == 9) ? 1.f : 0.f;
      w[t] = f2bf(v);
    }
    *(u16x4*)(ax + r * 32 + kq * 8) = *(u16x4*)w;
    *(u16x4*)(ax + r * 32 + kq * 8 + 4) = *(u16x4*)(w + 4);
  }
  __syncthreads();

  { // GEMM1: o-range 32/wave, single K step
    f32x4 c1[2][2];
#pragma unroll
    for (int mf = 0; mf < 2; ++mf)
#pragma unroll
      for (int nf = 0; nf < 2; ++nf) c1[mf][nf] = (f32x4){0.f, 0.f, 0.f, 0.f};
    const int oo = wid * 32;
    bf16x8 a0 = *(const bf16x8*)(ax + (size_t)col * 32 + qd * 8);
    bf16x8 a1 = *(const bf16x8*)(ax + (size_t)(16 + col) * 32 + qd * 8);
#pragma unroll
    for (int nf = 0; nf < 2; ++nf) {
      bf16x8 bv = *(const bf16x8*)(w1e + (size_t)(oo + nf * 16 + col) * 32 + qd * 8);
      c1[0][nf] = mfma16(a0, bv, c1[0][nf]);
      c1[1][nf] = mfma16(a1, bv, c1[1][nf]);
    }
#pragma unroll
    for (int nf = 0; nf < 2; ++nf) {
      const int o = oo + nf * 16 + col;
#pragma unroll
      for (int mf = 0; mf < 2; ++mf)
#pragma unroll
        for (int j = 0; j < 4; ++j)
          g1s[(mf * 16 + qd * 4 + j) * 264 + o] = f2bf(siluf(c1[mf][nf][j]));
    }
  }
  __syncthreads();

  // GEMM2: o-range 96/wave; mf=0 side A rows, mf=1 side B rows
  f32x4 acc[2][6];
#pragma unroll
  for (int mf = 0; mf < 2; ++mf)
#pragma unroll
    for (int nf = 0; nf < 6; ++nf) acc[mf][nf] = (f32x4){0.f, 0.f, 0.f, 0.f};
  const int o0 = wid * 96;
  for (int kk = 0; kk < 256; kk += 32) {
    bf16x8 a0 = *(const bf16x8*)(g1s + col * 264 + kk + qd * 8);
    bf16x8 a1 = *(const bf16x8*)(g1s + (16 + col) * 264 + kk + qd * 8);
#pragma unroll
    for (int nf = 0; nf < 6; ++nf) {
      bf16x8 bv = *(const bf16x8*)(zw2 + (size_t)(o0 + nf * 16 + col) * 256 + kk + qd * 8);
      acc[0][nf] = mfma16(a0, bv, acc[0][nf]);
      acc[1][nf] = mfma16(a1, bv, acc[1][nf]);
    }
  }
#pragma unroll
  for (int nf = 0; nf < 6; ++nf) {
    const float bias = zb2[o0 + nf * 16 + col];
#pragma unroll
    for (int mf = 0; mf < 2; ++mf)
#pragma unroll
      for (int j = 0; j < 4; ++j) acc[mf][nf][j] = siluf(acc[mf][nf][j] + bias);
  }
  float s[2][4], ss[2][4];
#pragma unroll
  for (int mf = 0; mf < 2; ++mf)
#pragma unroll
    for (int j = 0; j < 4; ++j) {
      float a = 0.f, b = 0.f;
#pragma unroll
      for (int nf = 0; nf < 6; ++nf) { float v = acc[mf][nf][j]; a += v; b += v * v; }
      s[mf][j] = a; ss[mf][j] = b;
    }
#pragma unroll
  for (int m = 1; m < 16; m <<= 1) {
#pragma unroll
    for (int mf = 0; mf < 2; ++mf)
#pragma unroll
      for (int j = 0; j < 4; ++j) {
        s[mf][j] += __shfl_xor(s[mf][j], m, 16);
        ss[mf][j] += __shfl_xor(ss[mf][j], m, 16);
      }
  }
  if (col == 0) {
#pragma unroll
    for (int mf = 0; mf < 2; ++mf)
#pragma unroll
      for (int j = 0; j < 4; ++j) {
        sArr[mf][wid][qd * 4 + j] = s[mf][j];
        ssArr[mf][wid][qd * 4 + j] = ss[mf][j];
      }
  }
  __syncthreads();
  float mean[2][4], rstd[2][4];
#pragma unroll
  for (int mf = 0; mf < 2; ++mf)
#pragma unroll
    for (int j = 0; j < 4; ++j) {
      const int e = qd * 4 + j;
      float S = 0.f, SS = 0.f;
#pragma unroll
      for (int w = 0; w < 8; ++w) { S += sArr[mf][w][e]; SS += ssArr[mf][w][e]; }
      float mu = S * (1.f / 768.f);
      mean[mf][j] = mu;
      rstd[mf][j] = rsqrtf(fmaxf(SS * (1.f / 768.f) - mu * mu, 0.f) + 1e-5f);
    }
#pragma unroll
  for (int nf = 0; nf < 6; ++nf) {
    const int o = o0 + nf * 16 + col;
    const float gv = lng[o], bv = lnb[o];
#pragma unroll
    for (int j = 0; j < 4; ++j) {
      const int e = qd * 4 + j;
      float va = (acc[0][nf][j] - mean[0][j]) * rstd[0][j] * gv + bv;
      float vb = (acc[1][nf][j] - mean[1][j]) * rstd[1][j] * gv + bv;
      const size_t ix = (size_t)(e0 + e) * 768 + o;
      prod[ix] = f2bf(bf2f(prod[ix]) * (va + vb));
    }
  }
}

// ---------------------------------------------------------------------------
// K_final: 32 edges/block, 512 threads
// ---------------------------------------------------------------------------
__global__ __launch_bounds__(512) void k_final(
    const float* __restrict__ Z, const int* __restrict__ tei, int E,
    const u16* __restrict__ ZXT,
    const u16* __restrict__ zxw, const float* __restrict__ zxb,
    const float* __restrict__ lng, const float* __restrict__ lnb,
    const u16* __restrict__ prod,
    const float* __restrict__ lw, const float* __restrict__ lb,
    float* __restrict__ out)
{
  __shared__ __align__(16) u16 ql[32 * 392];
  __shared__ __align__(16) u16 tl[32 * 264];
  __shared__ float sArr[8][32], ssArr[8][32], oArr[8][32];
  __shared__ int sidx[64];
  const int tid = threadIdx.x;
  const int lane = tid & 63, wid = tid >> 6;
  const int col = lane & 15, qd = lane >> 4;
  const int e0 = blockIdx.x * 32;

  if (tid < 32) sidx[tid] = tei[e0 + tid];
  else if (tid < 64) sidx[tid] = tei[E + e0 + (tid - 32)];
  __syncthreads();

  for (int e = wid; e < 32; e += 8) {
    const float2* zi = (const float2*)(Z + (size_t)sidx[e] * 384);
    const float2* zj = (const float2*)(Z + (size_t)sidx[32 + e] * 384);
    u16x2* qp = (u16x2*)(ql + e * 392);
#pragma unroll
    for (int p = 0; p < 3; ++p) {
      float2 a = zi[p * 64 + lane], b = zj[p * 64 + lane];
      u16x2 r;
      r[0] = f2bf(a.x * b.x); r[1] = f2bf(a.y * b.y);
      qp[p * 64 + lane] = r;
    }
  }
  __syncthreads();

  { // t-GEMM: o-range 32/wave, K=384
    f32x4 acc1[2][2];
#pragma unroll
    for (int mf = 0; mf < 2; ++mf)
#pragma unroll
      for (int nf = 0; nf < 2; ++nf) acc1[mf][nf] = (f32x4){0.f, 0.f, 0.f, 0.f};
    const int oo = wid * 32;
    for (int kk = 0; kk < 384; kk += 32) {
      bf16x8 a0 = *(const bf16x8*)(ql + col * 392 + kk + qd * 8);
      bf16x8 a1 = *(const bf16x8*)(ql + (16 + col) * 392 + kk + qd * 8);
#pragma unroll
      for (int nf = 0; nf < 2; ++nf) {
        bf16x8 bv = *(const bf16x8*)(ZXT + (size_t)(oo + nf * 16 + col) * 384 + kk + qd * 8);
        acc1[0][nf] = mfma16(a0, bv, acc1[0][nf]);
        acc1[1][nf] = mfma16(a1, bv, acc1[1][nf]);
      }
    }
#pragma unroll
    for (int nf = 0; nf < 2; ++nf) {
      const int o = oo + nf * 16 + col;
#pragma unroll
      for (int mf = 0; mf < 2; ++mf)
#pragma unroll
        for (int j = 0; j < 4; ++j)
          tl[(mf * 16 + qd * 4 + j) * 264 + o] = f2bf(acc1[mf][nf][j]);
    }
  }
  __syncthreads();

  // xzx GEMM: o-range 96/wave
  f32x4 acc[2][6];
#pragma unroll
  for (int mf = 0; mf < 2; ++mf)
#pragma unroll
    for (int nf = 0; nf < 6; ++nf) acc[mf][nf] = (f32x4){0.f, 0.f, 0.f, 0.f};
  const int o0 = wid * 96;
  for (int kk = 0; kk < 256; kk += 32) {
    bf16x8 a0 = *(const bf16x8*)(tl + col * 264 + kk + qd * 8);
    bf16x8 a1 = *(const bf16x8*)(tl + (16 + col) * 264 + kk + qd * 8);
#pragma unroll
    for (int nf = 0; nf < 6; ++nf) {
      bf16x8 bv = *(const bf16x8*)(zxw + (size_t)(o0 + nf * 16 + col) * 256 + kk + qd * 8);
      acc[0][nf] = mfma16(a0, bv, acc[0][nf]);
      acc[1][nf] = mfma16(a1, bv, acc[1][nf]);
    }
  }
#pragma unroll
  for (int nf = 0; nf < 6; ++nf) {
    const float bias = zxb[o0 + nf * 16 + col];
#pragma unroll
    for (int mf = 0; mf < 2; ++mf)
#pragma unroll
      for (int j = 0; j < 4; ++j) acc[mf][nf][j] += bias;
  }
  float s[2][4], ss[2][4];
#pragma unroll
  for (int mf = 0; mf < 2; ++mf)
#pragma unroll
    for (int j = 0; j < 4; ++j) {
      float a = 0.f, b = 0.f;
#pragma unroll
      for (int nf = 0; nf < 6; ++nf) { float v = acc[mf][nf][j]; a += v; b += v * v; }
      s[mf][j] = a; ss[mf][j] = b;
    }
#pragma unroll
  for (int m = 1; m < 16; m <<= 1) {
#pragma unroll
    for (int mf = 0; mf < 2; ++mf)
#pragma unroll
      for (int j = 0; j < 4; ++j) {
        s[mf][j] += __shfl_xor(s[mf][j], m, 16);
        ss[mf][j] += __shfl_xor(ss[mf][j], m, 16);
      }
  }
  if (col == 0) {
#pragma unroll
    for (int mf = 0; mf < 2; ++mf)
#pragma unroll
      for (int j = 0; j < 4; ++j) {
        sArr[wid][mf * 16 + qd * 4 + j] = s[mf][j];
        ssArr[wid][mf * 16 + qd * 4 + j] = ss[mf][j];
      }
  }
  __syncthreads();
  float mean[2][4], rstd[2][4];
#pragma unroll
  for (int mf = 0; mf < 2; ++mf)
#pragma unroll
    for (int j = 0; j < 4; ++j) {
      const int e = mf * 16 + qd * 4 + j;
      float S = 0.f, SS = 0.f;
#pragma unroll
      for (int w = 0; w < 8; ++w) { S += sArr[w][e]; SS += ssArr[w][e]; }
      float mu = S * (1.f / 768.f);
      mean[mf][j] = mu;
      rstd[mf][j] = rsqrtf(fmaxf(SS * (1.f / 768.f) - mu * mu, 0.f) + 1e-5f);
    }
  float pacc[2][4];
#pragma unroll
  for (int mf = 0; mf < 2; ++mf)
#pragma unroll
    for (int j = 0; j < 4; ++j) pacc[mf][j] = 0.f;
#pragma unroll
  for (int nf = 0; nf < 6; ++nf) {
    const int o = o0 + nf * 16 + col;
    const float gv = lng[o], bvq = lnb[o], lwv = lw[o];
#pragma unroll
    for (int mf = 0; mf < 2; ++mf)
#pragma unroll
      for (int j = 0; j < 4; ++j) {
        const int e = mf * 16 + qd * 4 + j;
        float xv = (acc[mf][nf][j] - mean[mf][j]) * rstd[mf][j] * gv + bvq;
        pacc[mf][j] += bf2f(prod[(size_t)(e0 + e) * 768 + o]) * xv * lwv;
      }
  }
#pragma unroll
  for (int m = 1; m < 16; m <<= 1) {
#pragma unroll
    for (int mf = 0; mf < 2; ++mf)
#pragma unroll
      for (int j = 0; j < 4; ++j) pacc[mf][j] += __shfl_xor(pacc[mf][j], m, 16);
  }
  if (col == 0) {
#pragma unroll
    for (int mf = 0; mf < 2; ++mf)
#pragma unroll
      for (int j = 0; j < 4; ++j) oArr[wid][mf * 16 + qd * 4 + j] = pacc[mf][j];
  }
  __syncthreads();
  if (tid < 32) {
    float v = lb[0];
#pragma unroll
    for (int w = 0; w < 8; ++w) v += oArr[w][tid];
    out[e0 + tid] = v;
  }
}

// ---------------------------------------------------------------------------
extern "C" void kernel_launch(void* const* d_in, const int* in_sizes, int n_in,
                              void* d_out, int out_size, void* d_ws, size_t ws_size,
                              hipStream_t stream)
{
  const float* x    = (const float*)d_in[0];
  const float* Z    = (const float*)d_in[1];
  const int*   tei  = (const int*)d_in[3];
  const float* xw1  = (const float*)d_in[4];
  const float* xb1  = (const float*)d_in[5];
  const float* xw2  = (const float*)d_in[6];
  const float* xb2  = (const float*)d_in[7];
  const float* xlg  = (const float*)d_in[8];
  const float* xlb  = (const float*)d_in[9];
  const float* zw1  = (const float*)d_in[10];
  const float* zb1  = (const float*)d_in[11];
  const float* zw2  = (const float*)d_in[12];
  const float* zb2  = (const float*)d_in[13];
  const float* zlg  = (const float*)d_in[14];
  const float* zlb  = (const float*)d_in[15];
  const float* zcw  = (const float*)d_in[16];
  const float* zcb  = (const float*)d_in[17];
  const float* zxw  = (const float*)d_in[18];
  const float* zxb  = (const float*)d_in[19];
  const float* zxlg = (const float*)d_in[20];
  const float* zxlb = (const float*)d_in[21];
  const float* lw   = (const float*)d_in[22];
  const float* lb   = (const float*)d_in[23];

  const int N = in_sizes[0] / 256;
  const int E = in_sizes[3] / 2;
  if (E <= 0) return;

  char* ws = (char*)d_ws;
  // Region 0 (overlaid): [Zt | xt | Pbuf] early; prod later (k_xij onward)
  u16* prod = (u16*)ws;                                   // E*768 bf16 = 201.3 MB
  u16* Zt   = (u16*)ws;                                   // 384*KP bf16 = 77.1 MB
  u16* xt   = (u16*)(ws + (size_t)384 * KP * 2);          // 256*KP bf16 = 51.4 MB
  float* Pbuf = (float*)(ws + (size_t)640 * KP * 2);      // 98*384*256 f32 = 38.5 MB
  size_t off = (size_t)E * 768 * sizeof(u16);
  float* Gbuf = (float*)(ws + off);           off += (size_t)384 * 256 * 4;
  float* xsum = (float*)(ws + off);           off += 256 * 4;
  u16* ZXT  = (u16*)(ws + off);               off += (size_t)256 * 384 * 2;
  u16* xw1b = (u16*)(ws + off);               off += (size_t)65536 * 2;
  u16* xw2b = (u16*)(ws + off);               off += (size_t)196608 * 2;
  u16* zw2b = (u16*)(ws + off);               off += (size_t)196608 * 2;
  u16* zxwb = (u16*)(ws + off);               off += (size_t)196608 * 2;
  u16* w1e  = (u16*)(ws + off);               off += (size_t)256 * 32 * 2;
  float* rxz = (float*)(ws + off);            off += (size_t)E * 12 * 4;

  hipMemsetAsync(xsum, 0, 256 * sizeof(float), stream);

  k_f2bf<<<dim3(65536 / 256), 256, 0, stream>>>(xw1, xw1b, 65536);
  k_f2bf<<<dim3(196608 / 256), 256, 0, stream>>>(xw2, xw2b, 196608);
  k_f2bf<<<dim3(196608 / 256), 256, 0, stream>>>(zw2, zw2b, 196608);
  k_f2bf<<<dim3(196608 / 256), 256, 0, stream>>>(zxw, zxwb, 196608);
  k_w1e<<<dim3(1), 256, 0, stream>>>(zw1, zb1, w1e);

  // ZX pipeline: transpose -> split-K MFMA -> reduce -> zxt
  k_tr<<<dim3(KP / 64, 6), 256, 0, stream>>>(Z, Zt, 384);
  k_tr<<<dim3(KP / 64, 4), 256, 0, stream>>>(x, xt, 256);
  k_mmzx<<<dim3(2, 3, 98), 256, 0, stream>>>(Zt, xt, Pbuf);
  k_redG<<<dim3(384), 256, 0, stream>>>(Pbuf, Gbuf);
  k_xsum<<<dim3(128), 256, 0, stream>>>(x, xsum, N);
  const float coeff = 1.f / (sqrtf((float)N) * 3840.f);
  k_zxt<<<dim3(384), 256, 0, stream>>>(Gbuf, xsum, zcw, zcb, ZXT, coeff);

  k_rxz<<<dim3(E / 4), 256, 0, stream>>>(Z, tei, E, rxz);
  // prod region (overwrites Zt/xt/Pbuf — dead after k_redG)
  k_xij<<<dim3(E / 32), 512, 0, stream>>>(x, tei, E, xw1b, xb1, xw2b, xb2, xlg, xlb, prod);
  k_xz2<<<dim3(E / 16), 512, 0, stream>>>(rxz, E, w1e, zw2b, zb2, zlg, zlb, prod);
  k_final<<<dim3(E / 32), 512, 0, stream>>>(Z, tei, E, ZXT, zxwb, zxb, zxlg, zxlb, prod, lw, lb, (float*)d_out);
}